// Round 21
// baseline (209.967 us; speedup 1.0000x reference)
//
#include <hip/hip_runtime.h>
#include <math.h>

// ---------------------------------------------------------------------------
// ROUND 21: halve the attention critical paths (all blocks are co-resident,
// so duration == longest block's serial chain).
//  - p32 local: split-K S=4 (32 tile_steps, uniform with p16)
//  - global attn: split-K S=4 (32 tile_steps)
//  - go/gll overlay dead po/pl; xcast+wcast merged into one launch
// ---------------------------------------------------------------------------

typedef __attribute__((ext_vector_type(8))) short bf16x8;
typedef __attribute__((ext_vector_type(4))) short bf16x4;
typedef __attribute__((ext_vector_type(4))) float f32x4;

__device__ inline float bf2f(unsigned short u) {
  union { unsigned int i; float f; } v; v.i = ((unsigned int)u) << 16; return v.f;
}
__device__ inline unsigned short f2bf(float x) {
  union { float f; unsigned int i; } v; v.f = x;
  return (unsigned short)((v.i + 0x7FFFu + ((v.i >> 16) & 1u)) >> 16);
}
__device__ inline unsigned cvtpk(float lo, float hi) {
  unsigned r;
  asm("v_cvt_pk_bf16_f32 %0, %1, %2" : "=v"(r) : "v"(lo), "v"(hi));
  return r;
}

#define CEXP_SCALE 0.25503485947f   /* 32^-0.5 * log2(e) */

// ---- merged casts: x->bf16 (blocks 0..4095) + weights (blocks 4096..5631) --
__global__ __launch_bounds__(256) void msa_cast_r21(
    const float* __restrict__ x, const float* __restrict__ Wq,
    const float* __restrict__ Wkv, const float* __restrict__ Wlkv,
    const float* __restrict__ Wproj, unsigned short* __restrict__ xb,
    unsigned short* __restrict__ Wqkvt, unsigned short* __restrict__ Wlkvt,
    unsigned short* __restrict__ Wprjt)
{
  if (blockIdx.x < 4096) {
    const size_t i = ((size_t)blockIdx.x * 256 + threadIdx.x) * 8;
    const float4 v0 = *reinterpret_cast<const float4*>(&x[i]);
    const float4 v1 = *reinterpret_cast<const float4*>(&x[i + 4]);
    bf16x8 o;
    o[0] = (short)f2bf(v0.x); o[1] = (short)f2bf(v0.y);
    o[2] = (short)f2bf(v0.z); o[3] = (short)f2bf(v0.w);
    o[4] = (short)f2bf(v1.x); o[5] = (short)f2bf(v1.y);
    o[6] = (short)f2bf(v1.z); o[7] = (short)f2bf(v1.w);
    *reinterpret_cast<bf16x8*>(&xb[i]) = o;
    return;
  }
  const int id = (blockIdx.x - 4096) * 256 + threadIdx.x;
  if (id < 196608) {
    const int r = id >> 8, k = id & 255;
    const float v = (r < 256) ? Wq[(size_t)k * 256 + r] : Wkv[(size_t)k * 512 + (r - 256)];
    Wqkvt[id] = f2bf(v);
  } else if (id < 327680) {
    const int j = id - 196608;
    const int n = j >> 8, k = j & 255;
    Wlkvt[j] = f2bf(Wlkv[(size_t)k * 512 + n]);
  } else if (id < 393216) {
    const int j = id - 327680;
    const int n = j >> 8, k = j & 255;
    Wprjt[j] = f2bf(Wproj[(size_t)k * 256 + n]);
  }
}

// ---- MFMA GEMM with XCD swizzle (bf16 A); cols < qcols CEXP-scaled --------
__global__ __launch_bounds__(256) void msa_gemm_mfma_r21(
    const unsigned short* __restrict__ Ab, const unsigned short* __restrict__ Wt,
    const float* __restrict__ bias, float* __restrict__ Cf,
    unsigned short* __restrict__ Cb, int K, int N, int qcols)
{
  __shared__ __align__(16) unsigned short A_lds[128][40];
  __shared__ __align__(16) unsigned short B_lds[128][40];

  const int tid = threadIdx.x;
  const int wave = tid >> 6, lane = tid & 63;
  const int l15 = lane & 15, g = lane >> 4;

  const int gx = gridDim.x;
  const int nwg = gx * gridDim.y;
  const int lin = blockIdx.y * gx + blockIdx.x;
  const int qq = nwg >> 3;
  const int virt = (lin & 7) * qq + (lin >> 3);
  const int by = virt / gx, bx = virt - by * gx;
  const int bm = by * 128, bn = bx * 128;

  const int wr = (wave >> 1) * 64, wc = (wave & 1) * 64;

  f32x4 acc[4][4] = {};

  for (int k0 = 0; k0 < K; k0 += 32) {
    __syncthreads();
#pragma unroll
    for (int s = 0; s < 2; ++s) {
      const int id = tid + s * 256;
      const int row = id >> 2, sg = (id & 3) << 3;
      *reinterpret_cast<bf16x8*>(&A_lds[row][sg]) =
          *reinterpret_cast<const bf16x8*>(&Ab[(size_t)(bm + row) * K + k0 + sg]);
      *reinterpret_cast<bf16x8*>(&B_lds[row][sg]) =
          *reinterpret_cast<const bf16x8*>(&Wt[(size_t)(bn + row) * K + k0 + sg]);
    }
    __syncthreads();

    bf16x8 a_frag[4], b_frag[4];
#pragma unroll
    for (int mi = 0; mi < 4; ++mi)
      a_frag[mi] = *reinterpret_cast<const bf16x8*>(&A_lds[wr + mi * 16 + l15][g << 3]);
#pragma unroll
    for (int ni = 0; ni < 4; ++ni)
      b_frag[ni] = *reinterpret_cast<const bf16x8*>(&B_lds[wc + ni * 16 + l15][g << 3]);
#pragma unroll
    for (int mi = 0; mi < 4; ++mi)
#pragma unroll
      for (int ni = 0; ni < 4; ++ni)
        acc[mi][ni] = __builtin_amdgcn_mfma_f32_16x16x32_bf16(
            a_frag[mi], b_frag[ni], acc[mi][ni], 0, 0, 0);
  }

#pragma unroll
  for (int mi = 0; mi < 4; ++mi)
#pragma unroll
    for (int ni = 0; ni < 4; ++ni) {
      const int col = bn + wc + ni * 16 + l15;
      const float cs = (col < qcols) ? CEXP_SCALE : 1.0f;
#pragma unroll
      for (int i = 0; i < 4; ++i) {
        const int row = bm + wr + mi * 16 + g * 4 + i;
        float v = acc[mi][ni][i];
        if (bias) v += bias[col];
        v *= cs;
        const size_t idx = (size_t)row * N + col;
        if (Cb) Cb[idx] = f2bf(v); else Cf[idx] = v;
      }
    }
}

// ---- one q-tile step ------------------------------------------------------
__device__ inline void tile_step_r21(
    const bf16x8 k0, const bf16x8 k1, const bf16x8 v0, const bf16x8 v1,
    const bf16x8 ones, const bf16x8 qf, f32x4& o0, f32x4& o1, f32x4& o2)
{
  const f32x4 zc = {0.f, 0.f, 0.f, 0.f};
  const f32x4 st0 = __builtin_amdgcn_mfma_f32_16x16x32_bf16(k0, qf, zc, 0, 0, 0);
  const f32x4 st1 = __builtin_amdgcn_mfma_f32_16x16x32_bf16(k1, qf, zc, 0, 0, 0);
  const float e00 = exp2f(st0[0]);
  const float e01 = exp2f(st0[1]);
  const float e02 = exp2f(st0[2]);
  const float e03 = exp2f(st0[3]);
  const float e10 = exp2f(st1[0]);
  const float e11 = exp2f(st1[1]);
  const float e12 = exp2f(st1[2]);
  const float e13 = exp2f(st1[3]);
  const unsigned u0 = cvtpk(e00, e01);
  const unsigned u1 = cvtpk(e02, e03);
  const unsigned u2 = cvtpk(e10, e11);
  const unsigned u3 = cvtpk(e12, e13);
  uint4 pu = make_uint4(u0, u1, u2, u3);
  const bf16x8 pb = *reinterpret_cast<const bf16x8*>(&pu);
  o2 = __builtin_amdgcn_mfma_f32_16x16x32_bf16(ones, pb, o2, 0, 0, 0);
  o0 = __builtin_amdgcn_mfma_f32_16x16x32_bf16(v0, pb, o0, 0, 0, 0);
  o1 = __builtin_amdgcn_mfma_f32_16x16x32_bf16(v1, pb, o1, 0, 0, 0);
}

// ---- merged LOCAL attention -----------------------------------------------
// fx: [0,128) p32 S=4 | [128,160) p16 | [160,288) p8 | [288,320) p4 scalar
__global__ __launch_bounds__(256) void msa_attn_local_r21(
    const unsigned short* __restrict__ xqkv, unsigned short* __restrict__ attnb,
    float* __restrict__ po, float* __restrict__ pl)
{
  __shared__ __align__(16) unsigned short K_lds[64][40];
  __shared__ __align__(16) unsigned short V_lds[32][68];

  const int fx = blockIdx.x;
  const int b = blockIdx.y;
  const int tid = threadIdx.x;

  bf16x8 ones;
#pragma unroll
  for (int i = 0; i < 8; ++i) ones[i] = (short)0x3F80;

  if (fx >= 288) {
    // p=4 heads (0,1): scalar tail
    const int j = fx - 288;
    const int head = j >> 4;
    const int nq = (j & 15) * 256 + tid;
    const int patch = nq >> 4;
    const int t = nq & 15;
    const int hb = patch >> 4, wb = patch & 15;
    const int n = (hb * 4 + (t >> 2)) * 64 + (wb * 4 + (t & 3));

    float qr[32];
    {
      const bf16x8* q8 = reinterpret_cast<const bf16x8*>(
          xqkv + ((size_t)b * 4096 + n) * 768 + head * 32);
#pragma unroll
      for (int i = 0; i < 4; ++i) {
        const bf16x8 v = q8[i];
#pragma unroll
        for (int jj = 0; jj < 8; ++jj) qr[i * 8 + jj] = bf2f((unsigned short)v[jj]);
      }
    }
    float l = 0.f;
    float acc[32] = {};
    const int kbase = (hb * 4) * 64 + wb * 4;
    for (int kk = 0; kk < 16; ++kk) {
      const int nk = kbase + (kk >> 2) * 64 + (kk & 3);
      const unsigned short* rowp = xqkv + ((size_t)b * 4096 + nk) * 768 + head * 32;
      const bf16x8* k8p = reinterpret_cast<const bf16x8*>(rowp + 256);
      const bf16x8* v8p = reinterpret_cast<const bf16x8*>(rowp + 512);
      float s = 0.f;
#pragma unroll
      for (int i = 0; i < 4; ++i) {
        const bf16x8 k8 = k8p[i];
#pragma unroll
        for (int jj = 0; jj < 8; ++jj) s = fmaf(qr[i * 8 + jj], bf2f((unsigned short)k8[jj]), s);
      }
      const float p = exp2f(s);
      l += p;
#pragma unroll
      for (int i = 0; i < 4; ++i) {
        const bf16x8 v8 = v8p[i];
#pragma unroll
        for (int jj = 0; jj < 8; ++jj)
          acc[i * 8 + jj] = fmaf(p, bf2f((unsigned short)v8[jj]), acc[i * 8 + jj]);
      }
    }
    const float inv = 1.f / l;
    unsigned short* dst = attnb + ((size_t)b * 4096 + nq) * 256 + head * 32;
#pragma unroll
    for (int c = 0; c < 32; ++c) dst[c] = f2bf(acc[c] * inv);
    return;
  }

  const int wave = tid >> 6, lane = tid & 63;
  const int q16 = lane & 15, h = lane >> 4;
  const int skey = tid >> 2;
  const int sh = tid & 3;

  if (fx >= 160) {
    // p=8 heads (2,3): 64q block == patch
    const int j = fx - 160;
    const int head = 2 + (j >> 6);
    const int patch = j & 63;
    const int hb = patch >> 3, wb = patch & 7;
    const int base = (hb * 8) * 64 + wb * 8;
    const int nq = patch * 64 + wave * 16 + q16;
    const int t = nq & 63;
    const int n = base + ((t >> 3) << 6) + (t & 7);

    const bf16x8 qfrag = *reinterpret_cast<const bf16x8*>(
        xqkv + ((size_t)b * 4096 + n) * 768 + head * 32 + 8 * h);

    f32x4 o0 = {0.f,0.f,0.f,0.f}, o1 = {0.f,0.f,0.f,0.f}, o2 = {0.f,0.f,0.f,0.f};
    {
      const int nk = base + ((skey >> 3) << 6) + (skey & 7);
      const unsigned short* row = xqkv + ((size_t)b * 4096 + nk) * 768 + head * 32;
      *reinterpret_cast<bf16x8*>(&K_lds[skey][8 * sh]) =
          *reinterpret_cast<const bf16x8*>(row + 256 + 8 * sh);
      const bf16x8 v = *reinterpret_cast<const bf16x8*>(row + 512 + 8 * sh);
#pragma unroll
      for (int jj = 0; jj < 8; ++jj)
        V_lds[8 * sh + jj][skey] = (unsigned short)v[jj];
    }
    __syncthreads();

#pragma unroll
    for (int sub = 0; sub < 2; ++sub) {
      const int s32 = sub * 32;
      const bf16x8 k0 = *reinterpret_cast<const bf16x8*>(&K_lds[s32 + q16][8 * h]);
      const bf16x8 k1 = *reinterpret_cast<const bf16x8*>(&K_lds[s32 + 16 + q16][8 * h]);
      const bf16x4 va0 = *reinterpret_cast<const bf16x4*>(&V_lds[q16][s32 + 4 * h]);
      const bf16x4 vb0 = *reinterpret_cast<const bf16x4*>(&V_lds[q16][s32 + 16 + 4 * h]);
      const bf16x4 va1 = *reinterpret_cast<const bf16x4*>(&V_lds[16 + q16][s32 + 4 * h]);
      const bf16x4 vb1 = *reinterpret_cast<const bf16x4*>(&V_lds[16 + q16][s32 + 16 + 4 * h]);
      bf16x8 v0, v1;
#pragma unroll
      for (int i = 0; i < 4; ++i) {
        v0[i] = va0[i]; v0[4 + i] = vb0[i];
        v1[i] = va1[i]; v1[4 + i] = vb1[i];
      }
      tile_step_r21(k0, k1, v0, v1, ones, qfrag, o0, o1, o2);
    }

    const float inv = 1.f / o2[0];
    unsigned short* dst = attnb + ((size_t)b * 4096 + nq) * 256 + head * 32;
    uint2 w0, w1;
    w0.x = (unsigned)f2bf(o0[0] * inv) | ((unsigned)f2bf(o0[1] * inv) << 16);
    w0.y = (unsigned)f2bf(o0[2] * inv) | ((unsigned)f2bf(o0[3] * inv) << 16);
    w1.x = (unsigned)f2bf(o1[0] * inv) | ((unsigned)f2bf(o1[1] * inv) << 16);
    w1.y = (unsigned)f2bf(o1[2] * inv) | ((unsigned)f2bf(o1[3] * inv) << 16);
    *reinterpret_cast<uint2*>(dst + 4 * h) = w0;
    *reinterpret_cast<uint2*>(dst + 16 + 4 * h) = w1;
    return;
  }

  // fx [0,128): p32 S=4 split-K; fx [128,160): p16 full-K
  int head, lp, xb2, split, kstart, kend;
  if (fx < 128) {
    head = 6 + (fx >> 6);
    const int r = fx & 63;
    xb2 = r >> 2; split = r & 3; lp = 5;
    kstart = split * 256; kend = kstart + 256;
  } else {
    const int j = fx - 128;
    head = 4 + (j >> 4); xb2 = j & 15; split = 0; lp = 4;
    kstart = 0; kend = 256;
  }
  const int p = 1 << lp;
  const int pm1 = p - 1;
  const int P2 = p * p;
  const int nbp = 64 >> lp;
  const int patch = (xb2 * 256) >> (2 * lp);
  const int hb = patch / nbp, wb = patch - (patch / nbp) * nbp;
  const int base = ((hb << lp)) * 64 + (wb << lp);

  const int q0 = xb2 * 256 + wave * 64;
  const int nqA = q0 + q16, nqB = q0 + 16 + q16, nqC = q0 + 32 + q16, nqD = q0 + 48 + q16;

  bf16x8 qfA, qfB, qfC, qfD;
  {
    int tt = nqA & (P2 - 1);
    qfA = *reinterpret_cast<const bf16x8*>(
        xqkv + ((size_t)b * 4096 + base + ((tt >> lp) << 6) + (tt & pm1)) * 768 + head * 32 + 8 * h);
    tt = nqB & (P2 - 1);
    qfB = *reinterpret_cast<const bf16x8*>(
        xqkv + ((size_t)b * 4096 + base + ((tt >> lp) << 6) + (tt & pm1)) * 768 + head * 32 + 8 * h);
    tt = nqC & (P2 - 1);
    qfC = *reinterpret_cast<const bf16x8*>(
        xqkv + ((size_t)b * 4096 + base + ((tt >> lp) << 6) + (tt & pm1)) * 768 + head * 32 + 8 * h);
    tt = nqD & (P2 - 1);
    qfD = *reinterpret_cast<const bf16x8*>(
        xqkv + ((size_t)b * 4096 + base + ((tt >> lp) << 6) + (tt & pm1)) * 768 + head * 32 + 8 * h);
  }

  f32x4 o0A = {0.f,0.f,0.f,0.f}, o1A = {0.f,0.f,0.f,0.f}, o2A = {0.f,0.f,0.f,0.f};
  f32x4 o0B = {0.f,0.f,0.f,0.f}, o1B = {0.f,0.f,0.f,0.f}, o2B = {0.f,0.f,0.f,0.f};
  f32x4 o0C = {0.f,0.f,0.f,0.f}, o1C = {0.f,0.f,0.f,0.f}, o2C = {0.f,0.f,0.f,0.f};
  f32x4 o0D = {0.f,0.f,0.f,0.f}, o1D = {0.f,0.f,0.f,0.f}, o2D = {0.f,0.f,0.f,0.f};

  {
    const int kk = kstart + skey;
    const int nk0 = base + ((kk >> lp) << 6) + (kk & pm1);
    const unsigned short* row = xqkv + ((size_t)b * 4096 + nk0) * 768 + head * 32;
    const bf16x8 kr = *reinterpret_cast<const bf16x8*>(row + 256 + 8 * sh);
    const bf16x8 vr = *reinterpret_cast<const bf16x8*>(row + 512 + 8 * sh);
    *reinterpret_cast<bf16x8*>(&K_lds[skey][8 * sh]) = kr;
#pragma unroll
    for (int jj = 0; jj < 8; ++jj)
      V_lds[8 * sh + jj][skey] = (unsigned short)vr[jj];
  }
  __syncthreads();

  for (int kc = kstart; kc < kend; kc += 64) {
    const bool more = (kc + 64) < kend;
    bf16x8 krn = {}, vrn = {};
    if (more) {
      const int kk = kc + 64 + skey;
      const int nk = base + ((kk >> lp) << 6) + (kk & pm1);
      const unsigned short* row = xqkv + ((size_t)b * 4096 + nk) * 768 + head * 32;
      krn = *reinterpret_cast<const bf16x8*>(row + 256 + 8 * sh);
      vrn = *reinterpret_cast<const bf16x8*>(row + 512 + 8 * sh);
    }

#pragma unroll
    for (int sub = 0; sub < 2; ++sub) {
      const int s32 = sub * 32;
      const bf16x8 k0 = *reinterpret_cast<const bf16x8*>(&K_lds[s32 + q16][8 * h]);
      const bf16x8 k1 = *reinterpret_cast<const bf16x8*>(&K_lds[s32 + 16 + q16][8 * h]);
      const bf16x4 va0 = *reinterpret_cast<const bf16x4*>(&V_lds[q16][s32 + 4 * h]);
      const bf16x4 vb0 = *reinterpret_cast<const bf16x4*>(&V_lds[q16][s32 + 16 + 4 * h]);
      const bf16x4 va1 = *reinterpret_cast<const bf16x4*>(&V_lds[16 + q16][s32 + 4 * h]);
      const bf16x4 vb1 = *reinterpret_cast<const bf16x4*>(&V_lds[16 + q16][s32 + 16 + 4 * h]);
      bf16x8 v0, v1;
#pragma unroll
      for (int i = 0; i < 4; ++i) {
        v0[i] = va0[i]; v0[4 + i] = vb0[i];
        v1[i] = va1[i]; v1[4 + i] = vb1[i];
      }
      tile_step_r21(k0, k1, v0, v1, ones, qfA, o0A, o1A, o2A);
      tile_step_r21(k0, k1, v0, v1, ones, qfB, o0B, o1B, o2B);
      tile_step_r21(k0, k1, v0, v1, ones, qfC, o0C, o1C, o2C);
      tile_step_r21(k0, k1, v0, v1, ones, qfD, o0D, o1D, o2D);
    }
    __syncthreads();
    if (more) {
      *reinterpret_cast<bf16x8*>(&K_lds[skey][8 * sh]) = krn;
#pragma unroll
      for (int jj = 0; jj < 8; ++jj)
        V_lds[8 * sh + jj][skey] = (unsigned short)vrn[jj];
    }
    __syncthreads();
  }

  if (lp == 4) {
#define R21L_EPI(O0, O1, O2, NQ)                                               \
    {                                                                          \
      const float inv = 1.f / O2[0];                                           \
      unsigned short* dst = attnb + ((size_t)b * 4096 + (NQ)) * 256 + head * 32;\
      uint2 w0, w1;                                                            \
      w0.x = (unsigned)f2bf(O0[0] * inv) | ((unsigned)f2bf(O0[1] * inv) << 16);\
      w0.y = (unsigned)f2bf(O0[2] * inv) | ((unsigned)f2bf(O0[3] * inv) << 16);\
      w1.x = (unsigned)f2bf(O1[0] * inv) | ((unsigned)f2bf(O1[1] * inv) << 16);\
      w1.y = (unsigned)f2bf(O1[2] * inv) | ((unsigned)f2bf(O1[3] * inv) << 16);\
      *reinterpret_cast<uint2*>(dst + 4 * h) = w0;                             \
      *reinterpret_cast<uint2*>(dst + 16 + 4 * h) = w1;                        \
    }
    R21L_EPI(o0A, o1A, o2A, nqA)
    R21L_EPI(o0B, o1B, o2B, nqB)
    R21L_EPI(o0C, o1C, o2C, nqC)
    R21L_EPI(o0D, o1D, o2D, nqD)
#undef R21L_EPI
  } else {
    // po[split 0..3][head2][b][nq][32], pl likewise
    const int head2 = head - 6;
    const size_t pb0 = ((((size_t)split * 2 + head2) * 8 + b) * 4096);
#define R21P_EPI(O0, O1, O2, NQ)                                               \
    {                                                                          \
      float* dst = po + (pb0 + (NQ)) * 32;                                     \
      float4 w0, w1;                                                           \
      w0.x = O0[0]; w0.y = O0[1]; w0.z = O0[2]; w0.w = O0[3];                  \
      w1.x = O1[0]; w1.y = O1[1]; w1.z = O1[2]; w1.w = O1[3];                  \
      *reinterpret_cast<float4*>(dst + 4 * h) = w0;                            \
      *reinterpret_cast<float4*>(dst + 16 + 4 * h) = w1;                       \
      if (h == 0) pl[pb0 + (NQ)] = O2[0];                                      \
    }
    R21P_EPI(o0A, o1A, o2A, nqA)
    R21P_EPI(o0B, o1B, o2B, nqB)
    R21P_EPI(o0C, o1C, o2C, nqC)
    R21P_EPI(o0D, o1D, o2D, nqD)
#undef R21P_EPI
  }
}

// ---- combine p32 partials (4 splits) -> attnb -----------------------------
__global__ __launch_bounds__(256) void msa_p32comb_r21(
    const float* __restrict__ po, const float* __restrict__ pl,
    unsigned short* __restrict__ attnb)
{
  const int e = blockIdx.x * 256 + threadIdx.x;
  const int b = blockIdx.y;
  const int head2 = e >> 17;
  const int rem = e & 131071;
  const int nq = rem >> 5, c = rem & 31;
  const size_t i0 = ((((size_t)0 * 2 + head2) * 8 + b) * 4096 + nq);
  const size_t i1 = ((((size_t)1 * 2 + head2) * 8 + b) * 4096 + nq);
  const size_t i2 = ((((size_t)2 * 2 + head2) * 8 + b) * 4096 + nq);
  const size_t i3 = ((((size_t)3 * 2 + head2) * 8 + b) * 4096 + nq);
  const float o = (po[i0 * 32 + c] + po[i1 * 32 + c])
                + (po[i2 * 32 + c] + po[i3 * 32 + c]);
  const float l = (pl[i0] + pl[i1]) + (pl[i2] + pl[i3]);
  attnb[((size_t)b * 4096 + nq) * 256 + (6 + head2) * 32 + c] = f2bf(o / l);
}

// ---- GLOBAL attention with S=4 key split ----------------------------------
// grid (16, 8, 8): x = xb2(4) x split(4); y = b; z = head
__global__ __launch_bounds__(256) void msa_attn_glob_r21(
    const unsigned short* __restrict__ Qg, const unsigned short* __restrict__ kv2,
    float* __restrict__ go, float* __restrict__ gll)
{
  __shared__ __align__(16) unsigned short K_lds[64][40];
  __shared__ __align__(16) unsigned short V_lds[32][68];

  const int tid = threadIdx.x;
  const int wave = tid >> 6, lane = tid & 63;
  const int q16 = lane & 15, h = lane >> 4;
  const int b = blockIdx.y;
  const int head = blockIdx.z;
  const int xb2 = blockIdx.x >> 2;
  const int split = blockIdx.x & 3;
  const int kstart = split * 256, kend = kstart + 256;

  bf16x8 ones;
#pragma unroll
  for (int i = 0; i < 8; ++i) ones[i] = (short)0x3F80;

  const int q0 = xb2 * 256 + wave * 64;
  const int nqA = q0 + q16, nqB = q0 + 16 + q16, nqC = q0 + 32 + q16, nqD = q0 + 48 + q16;

  const bf16x8 qfA = *reinterpret_cast<const bf16x8*>(
      Qg + ((size_t)b * 1024 + nqA) * 256 + head * 32 + 8 * h);
  const bf16x8 qfB = *reinterpret_cast<const bf16x8*>(
      Qg + ((size_t)b * 1024 + nqB) * 256 + head * 32 + 8 * h);
  const bf16x8 qfC = *reinterpret_cast<const bf16x8*>(
      Qg + ((size_t)b * 1024 + nqC) * 256 + head * 32 + 8 * h);
  const bf16x8 qfD = *reinterpret_cast<const bf16x8*>(
      Qg + ((size_t)b * 1024 + nqD) * 256 + head * 32 + 8 * h);

  f32x4 o0A = {0.f,0.f,0.f,0.f}, o1A = {0.f,0.f,0.f,0.f}, o2A = {0.f,0.f,0.f,0.f};
  f32x4 o0B = {0.f,0.f,0.f,0.f}, o1B = {0.f,0.f,0.f,0.f}, o2B = {0.f,0.f,0.f,0.f};
  f32x4 o0C = {0.f,0.f,0.f,0.f}, o1C = {0.f,0.f,0.f,0.f}, o2C = {0.f,0.f,0.f,0.f};
  f32x4 o0D = {0.f,0.f,0.f,0.f}, o1D = {0.f,0.f,0.f,0.f}, o2D = {0.f,0.f,0.f,0.f};

  const int skey = tid >> 2;
  const int sh = tid & 3;

  {
    const unsigned short* row = kv2 + ((size_t)b * 1024 + kstart + skey) * 512 + head * 32;
    const bf16x8 kr = *reinterpret_cast<const bf16x8*>(row + 8 * sh);
    const bf16x8 vr = *reinterpret_cast<const bf16x8*>(row + 256 + 8 * sh);
    *reinterpret_cast<bf16x8*>(&K_lds[skey][8 * sh]) = kr;
#pragma unroll
    for (int jj = 0; jj < 8; ++jj)
      V_lds[8 * sh + jj][skey] = (unsigned short)vr[jj];
  }
  __syncthreads();

  for (int kc = kstart; kc < kend; kc += 64) {
    const bool more = (kc + 64) < kend;
    bf16x8 krn = {}, vrn = {};
    if (more) {
      const unsigned short* row = kv2 + ((size_t)b * 1024 + kc + 64 + skey) * 512 + head * 32;
      krn = *reinterpret_cast<const bf16x8*>(row + 8 * sh);
      vrn = *reinterpret_cast<const bf16x8*>(row + 256 + 8 * sh);
    }

#pragma unroll
    for (int sub = 0; sub < 2; ++sub) {
      const int s32 = sub * 32;
      const bf16x8 k0 = *reinterpret_cast<const bf16x8*>(&K_lds[s32 + q16][8 * h]);
      const bf16x8 k1 = *reinterpret_cast<const bf16x8*>(&K_lds[s32 + 16 + q16][8 * h]);
      const bf16x4 va0 = *reinterpret_cast<const bf16x4*>(&V_lds[q16][s32 + 4 * h]);
      const bf16x4 vb0 = *reinterpret_cast<const bf16x4*>(&V_lds[q16][s32 + 16 + 4 * h]);
      const bf16x4 va1 = *reinterpret_cast<const bf16x4*>(&V_lds[16 + q16][s32 + 4 * h]);
      const bf16x4 vb1 = *reinterpret_cast<const bf16x4*>(&V_lds[16 + q16][s32 + 16 + 4 * h]);
      bf16x8 v0, v1;
#pragma unroll
      for (int i = 0; i < 4; ++i) {
        v0[i] = va0[i]; v0[4 + i] = vb0[i];
        v1[i] = va1[i]; v1[4 + i] = vb1[i];
      }
      tile_step_r21(k0, k1, v0, v1, ones, qfA, o0A, o1A, o2A);
      tile_step_r21(k0, k1, v0, v1, ones, qfB, o0B, o1B, o2B);
      tile_step_r21(k0, k1, v0, v1, ones, qfC, o0C, o1C, o2C);
      tile_step_r21(k0, k1, v0, v1, ones, qfD, o0D, o1D, o2D);
    }
    __syncthreads();
    if (more) {
      *reinterpret_cast<bf16x8*>(&K_lds[skey][8 * sh]) = krn;
#pragma unroll
      for (int jj = 0; jj < 8; ++jj)
        V_lds[8 * sh + jj][skey] = (unsigned short)vrn[jj];
    }
    __syncthreads();
  }

  // go[split 0..3][b][head][nq][32]
  const size_t gb0 = ((((size_t)split * 8 + b) * 8 + head) * 1024);
#define R21G_EPI(O0, O1, O2, NQ)                                               \
  {                                                                            \
    float* dst = go + (gb0 + (NQ)) * 32;                                       \
    float4 w0, w1;                                                             \
    w0.x = O0[0]; w0.y = O0[1]; w0.z = O0[2]; w0.w = O0[3];                    \
    w1.x = O1[0]; w1.y = O1[1]; w1.z = O1[2]; w1.w = O1[3];                    \
    *reinterpret_cast<float4*>(dst + 4 * h) = w0;                              \
    *reinterpret_cast<float4*>(dst + 16 + 4 * h) = w1;                         \
    if (h == 0) gll[gb0 + (NQ)] = O2[0];                                       \
  }
  R21G_EPI(o0A, o1A, o2A, nqA)
  R21G_EPI(o0B, o1B, o2B, nqB)
  R21G_EPI(o0C, o1C, o2C, nqC)
  R21G_EPI(o0D, o1D, o2D, nqD)
#undef R21G_EPI
}

// ---- combine global partials (4 splits) -> gl (f32) -----------------------
__global__ __launch_bounds__(256) void msa_globcomb_r21(
    const float* __restrict__ go, const float* __restrict__ gll,
    float* __restrict__ gl)
{
  const int e = blockIdx.x * 256 + threadIdx.x;
  const int b = blockIdx.y;
  const int head = e >> 15;
  const int rem = e & 32767;
  const int nq = rem >> 5, c = rem & 31;
  const size_t i0 = ((((size_t)0 * 8 + b) * 8 + head) * 1024 + nq);
  const size_t i1 = ((((size_t)1 * 8 + b) * 8 + head) * 1024 + nq);
  const size_t i2 = ((((size_t)2 * 8 + b) * 8 + head) * 1024 + nq);
  const size_t i3 = ((((size_t)3 * 8 + b) * 8 + head) * 1024 + nq);
  const float o = (go[i0 * 32 + c] + go[i1 * 32 + c])
                + (go[i2 * 32 + c] + go[i3 * 32 + c]);
  const float l = (gll[i0] + gll[i1]) + (gll[i2] + gll[i3]);
  gl[((size_t)b * 1024 + nq) * 256 + head * 32 + c] = o / l;
}

// ---- qg_reduce ------------------------------------------------------------
__global__ __launch_bounds__(256) void msa_qg_reduce_r21(
    const unsigned short* __restrict__ xqkv, float* __restrict__ qg_all)
{
  __shared__ float red[256];
  const int head = blockIdx.z;
  const int lp = (head < 2) ? 2 : (head < 4) ? 3 : (head < 6) ? 4 : 5;
  const int p = 1 << lp;
  const int P2 = p * p;
  const int nbp = 64 >> lp;
  const int npat = nbp * nbp;
  const int R = (lp <= 3) ? 8 : 1;
  const int total = P2 * 32 * R;
  const int gid = blockIdx.x * 256 + threadIdx.x;
  if (gid >= total) return;
  const int b = blockIdx.y;

  const int c = gid & 31;
  const int tr = gid >> 5;
  const int r = tr & (R - 1);
  const int t = tr >> ((R == 8) ? 3 : 0);
  const int hp = t >> lp, wp = t & (p - 1);

  const unsigned short* src = xqkv + (size_t)b * 4096 * 768 + head * 32 + c;
  float s = 0.f;
  for (int j = r; j < npat; j += R) {
    const int hb = j / nbp, wb = j - (j / nbp) * nbp;
    const int n = ((hb << lp) + hp) * 64 + (wb << lp) + wp;
    s += bf2f(src[(size_t)n * 768]);
  }

  if (R == 8) {
    red[threadIdx.x] = s;
    __syncthreads();
    if (r < 4) red[threadIdx.x] += red[threadIdx.x + 128];
    __syncthreads();
    if (r < 2) red[threadIdx.x] += red[threadIdx.x + 64];
    __syncthreads();
    if (r == 0) {
      s = red[threadIdx.x] + red[threadIdx.x + 32];
      qg_all[((size_t)b * 8 + head) * 32768 + (size_t)t * 32 + c] = s / (float)npat;
    }
  } else {
    qg_all[((size_t)b * 8 + head) * 32768 + (size_t)t * 32 + c] = s / (float)npat;
  }
}

// ---- bilinear upsample -> Qg bf16 -----------------------------------------
__global__ __launch_bounds__(256) void msa_qg_upsample_r21(
    const float* __restrict__ qg_all, unsigned short* __restrict__ Qg)
{
  const int head = blockIdx.z;
  const int p = (head < 2) ? 4 : (head < 4) ? 8 : (head < 6) ? 16 : 32;
  const int e = blockIdx.x * 256 + threadIdx.x;
  const int b = blockIdx.y;
  const int mlin = e >> 5, c = e & 31;
  const int mi = mlin >> 5, mj = mlin & 31;
  const float* src = qg_all + ((size_t)b * 8 + head) * 32768;
  float v;
  if (p == 32) {
    v = src[(size_t)mlin * 32 + c];
  } else {
    const float s = (float)p / 32.0f;
    const float xf = (mj + 0.5f) * s - 0.5f;
    const float yf = (mi + 0.5f) * s - 0.5f;
    const float xfl = floorf(xf), yfl = floorf(yf);
    const float fx = xf - xfl, fy = yf - yfl;
    const int x0 = (int)xfl, y0 = (int)yfl;
    const int x0c = max(0, min(p - 1, x0)), x1c = max(0, min(p - 1, x0 + 1));
    const int y0c = max(0, min(p - 1, y0)), y1c = max(0, min(p - 1, y0 + 1));
    const float v00 = src[(size_t)(y0c * p + x0c) * 32 + c];
    const float v01 = src[(size_t)(y0c * p + x1c) * 32 + c];
    const float v10 = src[(size_t)(y1c * p + x0c) * 32 + c];
    const float v11 = src[(size_t)(y1c * p + x1c) * 32 + c];
    v = (1.f - fy) * ((1.f - fx) * v00 + fx * v01)
      + fy * ((1.f - fx) * v10 + fx * v11);
  }
  Qg[((size_t)b * 1024 + mlin) * 256 + head * 32 + c] = f2bf(v);
}

// ---- 2x2 avg pool ---------------------------------------------------------
__global__ __launch_bounds__(256) void msa_pool_r21(
    const unsigned short* __restrict__ attn, unsigned short* __restrict__ pooled)
{
  const int c = threadIdx.x;
  const int mlin = blockIdx.x;
  const int b = blockIdx.y;
  const int mi = mlin >> 5, mj = mlin & 31;
  const size_t base = (size_t)b * 4096;
  const int r0 = mi * 2, q0 = mj * 2;
  float s = bf2f(attn[(base + (r0 * 64 + q0)) * 256 + c])
          + bf2f(attn[(base + (r0 * 64 + q0 + 1)) * 256 + c])
          + bf2f(attn[(base + ((r0 + 1) * 64 + q0)) * 256 + c])
          + bf2f(attn[(base + ((r0 + 1) * 64 + q0 + 1)) * 256 + c]);
  pooled[((size_t)b * 1024 + mlin) * 256 + c] = f2bf(s * 0.25f);
}

// ---- blend ----------------------------------------------------------------
__global__ __launch_bounds__(256) void msa_blend_r21(
    const float* __restrict__ gl, unsigned short* __restrict__ attn)
{
  const int c = threadIdx.x;
  const int n = blockIdx.x;
  const int b = blockIdx.y;
  const int hh = n >> 6, w = n & 63;
  const float xf = (w + 0.5f) * 0.5f - 0.5f;
  const float yf = (hh + 0.5f) * 0.5f - 0.5f;
  const float xfl = floorf(xf), yfl = floorf(yf);
  const float fx = xf - xfl, fy = yf - yfl;
  const int x0 = (int)xfl, y0 = (int)yfl;
  const int x0c = max(0, min(31, x0)), x1c = max(0, min(31, x0 + 1));
  const int y0c = max(0, min(31, y0)), y1c = max(0, min(31, y0 + 1));
  const float* g = gl + (size_t)b * 1024 * 256;
  const float v00 = g[(size_t)(y0c * 32 + x0c) * 256 + c];
  const float v01 = g[(size_t)(y0c * 32 + x1c) * 256 + c];
  const float v10 = g[(size_t)(y1c * 32 + x0c) * 256 + c];
  const float v11 = g[(size_t)(y1c * 32 + x1c) * 256 + c];
  const float v = (1.f - fy) * ((1.f - fx) * v00 + fx * v01)
                + fy * ((1.f - fx) * v10 + fx * v11);
  const size_t idx = ((size_t)b * 4096 + n) * 256 + c;
  attn[idx] = f2bf(bf2f(attn[idx]) + v);
}

extern "C" void kernel_launch(void* const* d_in, const int* in_sizes, int n_in,
                              void* d_out, int out_size, void* d_ws, size_t ws_size,
                              hipStream_t stream)
{
  const float* x     = (const float*)d_in[0];
  const float* Wq    = (const float*)d_in[1];
  const float* Wkv   = (const float*)d_in[2];
  const float* Wlkv  = (const float*)d_in[3];
  const float* Wproj = (const float*)d_in[4];
  const float* bproj = (const float*)d_in[5];

  char* ws = (char*)d_ws;
  unsigned short* xqkv  = (unsigned short*)(ws + 0);            // [32768,768] bf16
  unsigned short* attnb = (unsigned short*)(ws + 50331648ull);  // [32768,256] bf16
  unsigned short* Qg    = (unsigned short*)(ws + 67108864ull);  // [8192,256] bf16
  float* qg_all = (float*)(ws + 71303168ull);                   // [8,8,1024,32] f32
  unsigned short* Wqkvt = (unsigned short*)(ws + 79691776ull);  // [768,256] bf16
  unsigned short* Wlkvt = (unsigned short*)(ws + 80084992ull);  // [512,256] bf16
  unsigned short* Wprjt = (unsigned short*)(ws + 80347136ull);  // [256,256] bf16
  float* gl     = (float*)(ws + 80478208ull);                   // [8192,256] f32
  unsigned short* xb    = (unsigned short*)(ws + 88866816ull);  // [32768,256] bf16
  float* po  = (float*)(ws + 105644032ull);                     // [4][2][8][4096][32] = 33.6MB
  float* pl  = (float*)(ws + 139198464ull);                     // [4][2][8][4096] = 1.05MB
  float* go  = (float*)(ws + 105644032ull);                     // overlay po (dead after p32comb)
  float* gll = (float*)(ws + 139198464ull);                     // overlay pl (dead after p32comb)
  unsigned short* pooled = (unsigned short*)(ws + 0);           // over dead xqkv
  unsigned short* kv2    = (unsigned short*)(ws + 16777216ull); // over dead xqkv

  // 0) merged casts (x + all weights)
  msa_cast_r21<<<dim3(5632), 256, 0, stream>>>(x, Wq, Wkv, Wlkv, Wproj,
                                               xb, Wqkvt, Wlkvt, Wprjt);

  // 1) fused QKV projection (bf16 A; q cols CEXP-scaled)
  msa_gemm_mfma_r21<<<dim3(6, 256), 256, 0, stream>>>(
      xb, Wqkvt, nullptr, nullptr, xqkv, 256, 768, 256);

  // 2) global-query means + bilinear upsample
  msa_qg_reduce_r21<<<dim3(128, 8, 8), 256, 0, stream>>>(xqkv, qg_all);
  msa_qg_upsample_r21<<<dim3(128, 8, 8), 256, 0, stream>>>(qg_all, Qg);

  // 3) local windowed attention (p32 S=4, heavy-first) + combine
  msa_attn_local_r21<<<dim3(320, 8), 256, 0, stream>>>(xqkv, attnb, po, pl);
  msa_p32comb_r21<<<dim3(1024, 8), 256, 0, stream>>>(po, pl, attnb);

  // 4) pool + kv2 projection
  msa_pool_r21<<<dim3(1024, 8), 256, 0, stream>>>(attnb, pooled);
  msa_gemm_mfma_r21<<<dim3(4, 64), 256, 0, stream>>>(
      pooled, Wlkvt, nullptr, nullptr, kv2, 256, 512, 0);

  // 5) global cross-attention (S=4) + combine (go/gll overlay dead po/pl)
  msa_attn_glob_r21<<<dim3(16, 8, 8), 256, 0, stream>>>(Qg, kv2, go, gll);
  msa_globcomb_r21<<<dim3(1024, 8), 256, 0, stream>>>(go, gll, gl);

  // 6) blend + final projection
  msa_blend_r21<<<dim3(4096, 8), 256, 0, stream>>>(gl, attnb);
  msa_gemm_mfma_r21<<<dim3(2, 256), 256, 0, stream>>>(
      attnb, Wprjt, bproj, (float*)d_out, nullptr, 256, 256, 0);

  (void)in_sizes; (void)n_in; (void)out_size; (void)ws_size;
}

// Round 22
// 203.663 us; speedup vs baseline: 1.0310x; 1.0310x over previous
//
#include <hip/hip_runtime.h>
#include <math.h>

// ---------------------------------------------------------------------------
// ROUND 22: register double-buffered staging in the MFMA GEMM (r16's proven
// attention pattern): issue k+1 loads before computing k, ds_write after the
// read-barrier. Hides global latency under MFMA in the 8-step K loop.
// Everything else r21 (renamed _r22).
// ---------------------------------------------------------------------------

typedef __attribute__((ext_vector_type(8))) short bf16x8;
typedef __attribute__((ext_vector_type(4))) short bf16x4;
typedef __attribute__((ext_vector_type(4))) float f32x4;

__device__ inline float bf2f(unsigned short u) {
  union { unsigned int i; float f; } v; v.i = ((unsigned int)u) << 16; return v.f;
}
__device__ inline unsigned short f2bf(float x) {
  union { float f; unsigned int i; } v; v.f = x;
  return (unsigned short)((v.i + 0x7FFFu + ((v.i >> 16) & 1u)) >> 16);
}
__device__ inline unsigned cvtpk(float lo, float hi) {
  unsigned r;
  asm("v_cvt_pk_bf16_f32 %0, %1, %2" : "=v"(r) : "v"(lo), "v"(hi));
  return r;
}

#define CEXP_SCALE 0.25503485947f   /* 32^-0.5 * log2(e) */

// ---- merged casts ----------------------------------------------------------
__global__ __launch_bounds__(256) void msa_cast_r22(
    const float* __restrict__ x, const float* __restrict__ Wq,
    const float* __restrict__ Wkv, const float* __restrict__ Wlkv,
    const float* __restrict__ Wproj, unsigned short* __restrict__ xb,
    unsigned short* __restrict__ Wqkvt, unsigned short* __restrict__ Wlkvt,
    unsigned short* __restrict__ Wprjt)
{
  if (blockIdx.x < 4096) {
    const size_t i = ((size_t)blockIdx.x * 256 + threadIdx.x) * 8;
    const float4 v0 = *reinterpret_cast<const float4*>(&x[i]);
    const float4 v1 = *reinterpret_cast<const float4*>(&x[i + 4]);
    bf16x8 o;
    o[0] = (short)f2bf(v0.x); o[1] = (short)f2bf(v0.y);
    o[2] = (short)f2bf(v0.z); o[3] = (short)f2bf(v0.w);
    o[4] = (short)f2bf(v1.x); o[5] = (short)f2bf(v1.y);
    o[6] = (short)f2bf(v1.z); o[7] = (short)f2bf(v1.w);
    *reinterpret_cast<bf16x8*>(&xb[i]) = o;
    return;
  }
  const int id = (blockIdx.x - 4096) * 256 + threadIdx.x;
  if (id < 196608) {
    const int r = id >> 8, k = id & 255;
    const float v = (r < 256) ? Wq[(size_t)k * 256 + r] : Wkv[(size_t)k * 512 + (r - 256)];
    Wqkvt[id] = f2bf(v);
  } else if (id < 327680) {
    const int j = id - 196608;
    const int n = j >> 8, k = j & 255;
    Wlkvt[j] = f2bf(Wlkv[(size_t)k * 512 + n]);
  } else if (id < 393216) {
    const int j = id - 327680;
    const int n = j >> 8, k = j & 255;
    Wprjt[j] = f2bf(Wproj[(size_t)k * 256 + n]);
  }
}

// ---- MFMA GEMM, XCD swizzle, reg-double-buffered staging ------------------
__global__ __launch_bounds__(256) void msa_gemm_mfma_r22(
    const unsigned short* __restrict__ Ab, const unsigned short* __restrict__ Wt,
    const float* __restrict__ bias, float* __restrict__ Cf,
    unsigned short* __restrict__ Cb, int K, int N, int qcols)
{
  __shared__ __align__(16) unsigned short A_lds[128][40];
  __shared__ __align__(16) unsigned short B_lds[128][40];

  const int tid = threadIdx.x;
  const int wave = tid >> 6, lane = tid & 63;
  const int l15 = lane & 15, g = lane >> 4;

  const int gx = gridDim.x;
  const int nwg = gx * gridDim.y;
  const int lin = blockIdx.y * gx + blockIdx.x;
  const int qq = nwg >> 3;
  const int virt = (lin & 7) * qq + (lin >> 3);
  const int by = virt / gx, bx = virt - by * gx;
  const int bm = by * 128, bn = bx * 128;

  const int wr = (wave >> 1) * 64, wc = (wave & 1) * 64;

  // per-thread staging slots: s=0 -> id=tid, s=1 -> id=tid+256
  const int row0 = tid >> 2,          sg0 = (tid & 3) << 3;
  const int row1 = (tid + 256) >> 2,  sg1 = (tid & 3) << 3;   // (tid+256)&3 == tid&3

  f32x4 acc[4][4] = {};

  // prologue: load k0 = 0 into regs, write to LDS
  bf16x8 a0 = *reinterpret_cast<const bf16x8*>(&Ab[(size_t)(bm + row0) * K + sg0]);
  bf16x8 a1 = *reinterpret_cast<const bf16x8*>(&Ab[(size_t)(bm + row1) * K + sg1]);
  bf16x8 b0 = *reinterpret_cast<const bf16x8*>(&Wt[(size_t)(bn + row0) * K + sg0]);
  bf16x8 b1 = *reinterpret_cast<const bf16x8*>(&Wt[(size_t)(bn + row1) * K + sg1]);
  *reinterpret_cast<bf16x8*>(&A_lds[row0][sg0]) = a0;
  *reinterpret_cast<bf16x8*>(&A_lds[row1][sg1]) = a1;
  *reinterpret_cast<bf16x8*>(&B_lds[row0][sg0]) = b0;
  *reinterpret_cast<bf16x8*>(&B_lds[row1][sg1]) = b1;
  __syncthreads();

  for (int k0 = 0; k0 < K; k0 += 32) {
    const bool more = (k0 + 32) < K;
    bf16x8 an0 = {}, an1 = {}, bn0 = {}, bn1 = {};
    if (more) {
      const int kn = k0 + 32;
      an0 = *reinterpret_cast<const bf16x8*>(&Ab[(size_t)(bm + row0) * K + kn + sg0]);
      an1 = *reinterpret_cast<const bf16x8*>(&Ab[(size_t)(bm + row1) * K + kn + sg1]);
      bn0 = *reinterpret_cast<const bf16x8*>(&Wt[(size_t)(bn + row0) * K + kn + sg0]);
      bn1 = *reinterpret_cast<const bf16x8*>(&Wt[(size_t)(bn + row1) * K + kn + sg1]);
    }

    bf16x8 a_frag[4], b_frag[4];
#pragma unroll
    for (int mi = 0; mi < 4; ++mi)
      a_frag[mi] = *reinterpret_cast<const bf16x8*>(&A_lds[wr + mi * 16 + l15][g << 3]);
#pragma unroll
    for (int ni = 0; ni < 4; ++ni)
      b_frag[ni] = *reinterpret_cast<const bf16x8*>(&B_lds[wc + ni * 16 + l15][g << 3]);
#pragma unroll
    for (int mi = 0; mi < 4; ++mi)
#pragma unroll
      for (int ni = 0; ni < 4; ++ni)
        acc[mi][ni] = __builtin_amdgcn_mfma_f32_16x16x32_bf16(
            a_frag[mi], b_frag[ni], acc[mi][ni], 0, 0, 0);

    __syncthreads();          // everyone done reading this K-step's LDS
    if (more) {
      *reinterpret_cast<bf16x8*>(&A_lds[row0][sg0]) = an0;
      *reinterpret_cast<bf16x8*>(&A_lds[row1][sg1]) = an1;
      *reinterpret_cast<bf16x8*>(&B_lds[row0][sg0]) = bn0;
      *reinterpret_cast<bf16x8*>(&B_lds[row1][sg1]) = bn1;
    }
    __syncthreads();          // next K-step visible
  }

#pragma unroll
  for (int mi = 0; mi < 4; ++mi)
#pragma unroll
    for (int ni = 0; ni < 4; ++ni) {
      const int col = bn + wc + ni * 16 + l15;
      const float cs = (col < qcols) ? CEXP_SCALE : 1.0f;
#pragma unroll
      for (int i = 0; i < 4; ++i) {
        const int row = bm + wr + mi * 16 + g * 4 + i;
        float v = acc[mi][ni][i];
        if (bias) v += bias[col];
        v *= cs;
        const size_t idx = (size_t)row * N + col;
        if (Cb) Cb[idx] = f2bf(v); else Cf[idx] = v;
      }
    }
}

// ---- one q-tile step ------------------------------------------------------
__device__ inline void tile_step_r22(
    const bf16x8 k0, const bf16x8 k1, const bf16x8 v0, const bf16x8 v1,
    const bf16x8 ones, const bf16x8 qf, f32x4& o0, f32x4& o1, f32x4& o2)
{
  const f32x4 zc = {0.f, 0.f, 0.f, 0.f};
  const f32x4 st0 = __builtin_amdgcn_mfma_f32_16x16x32_bf16(k0, qf, zc, 0, 0, 0);
  const f32x4 st1 = __builtin_amdgcn_mfma_f32_16x16x32_bf16(k1, qf, zc, 0, 0, 0);
  const float e00 = exp2f(st0[0]);
  const float e01 = exp2f(st0[1]);
  const float e02 = exp2f(st0[2]);
  const float e03 = exp2f(st0[3]);
  const float e10 = exp2f(st1[0]);
  const float e11 = exp2f(st1[1]);
  const float e12 = exp2f(st1[2]);
  const float e13 = exp2f(st1[3]);
  const unsigned u0 = cvtpk(e00, e01);
  const unsigned u1 = cvtpk(e02, e03);
  const unsigned u2 = cvtpk(e10, e11);
  const unsigned u3 = cvtpk(e12, e13);
  uint4 pu = make_uint4(u0, u1, u2, u3);
  const bf16x8 pb = *reinterpret_cast<const bf16x8*>(&pu);
  o2 = __builtin_amdgcn_mfma_f32_16x16x32_bf16(ones, pb, o2, 0, 0, 0);
  o0 = __builtin_amdgcn_mfma_f32_16x16x32_bf16(v0, pb, o0, 0, 0, 0);
  o1 = __builtin_amdgcn_mfma_f32_16x16x32_bf16(v1, pb, o1, 0, 0, 0);
}

// ---- merged LOCAL attention -----------------------------------------------
// fx: [0,128) p32 S=4 | [128,160) p16 | [160,288) p8 | [288,320) p4 scalar
__global__ __launch_bounds__(256) void msa_attn_local_r22(
    const unsigned short* __restrict__ xqkv, unsigned short* __restrict__ attnb,
    float* __restrict__ po, float* __restrict__ pl)
{
  __shared__ __align__(16) unsigned short K_lds[64][40];
  __shared__ __align__(16) unsigned short V_lds[32][68];

  const int fx = blockIdx.x;
  const int b = blockIdx.y;
  const int tid = threadIdx.x;

  bf16x8 ones;
#pragma unroll
  for (int i = 0; i < 8; ++i) ones[i] = (short)0x3F80;

  if (fx >= 288) {
    const int j = fx - 288;
    const int head = j >> 4;
    const int nq = (j & 15) * 256 + tid;
    const int patch = nq >> 4;
    const int t = nq & 15;
    const int hb = patch >> 4, wb = patch & 15;
    const int n = (hb * 4 + (t >> 2)) * 64 + (wb * 4 + (t & 3));

    float qr[32];
    {
      const bf16x8* q8 = reinterpret_cast<const bf16x8*>(
          xqkv + ((size_t)b * 4096 + n) * 768 + head * 32);
#pragma unroll
      for (int i = 0; i < 4; ++i) {
        const bf16x8 v = q8[i];
#pragma unroll
        for (int jj = 0; jj < 8; ++jj) qr[i * 8 + jj] = bf2f((unsigned short)v[jj]);
      }
    }
    float l = 0.f;
    float acc[32] = {};
    const int kbase = (hb * 4) * 64 + wb * 4;
    for (int kk = 0; kk < 16; ++kk) {
      const int nk = kbase + (kk >> 2) * 64 + (kk & 3);
      const unsigned short* rowp = xqkv + ((size_t)b * 4096 + nk) * 768 + head * 32;
      const bf16x8* k8p = reinterpret_cast<const bf16x8*>(rowp + 256);
      const bf16x8* v8p = reinterpret_cast<const bf16x8*>(rowp + 512);
      float s = 0.f;
#pragma unroll
      for (int i = 0; i < 4; ++i) {
        const bf16x8 k8 = k8p[i];
#pragma unroll
        for (int jj = 0; jj < 8; ++jj) s = fmaf(qr[i * 8 + jj], bf2f((unsigned short)k8[jj]), s);
      }
      const float p = exp2f(s);
      l += p;
#pragma unroll
      for (int i = 0; i < 4; ++i) {
        const bf16x8 v8 = v8p[i];
#pragma unroll
        for (int jj = 0; jj < 8; ++jj)
          acc[i * 8 + jj] = fmaf(p, bf2f((unsigned short)v8[jj]), acc[i * 8 + jj]);
      }
    }
    const float inv = 1.f / l;
    unsigned short* dst = attnb + ((size_t)b * 4096 + nq) * 256 + head * 32;
#pragma unroll
    for (int c = 0; c < 32; ++c) dst[c] = f2bf(acc[c] * inv);
    return;
  }

  const int wave = tid >> 6, lane = tid & 63;
  const int q16 = lane & 15, h = lane >> 4;
  const int skey = tid >> 2;
  const int sh = tid & 3;

  if (fx >= 160) {
    const int j = fx - 160;
    const int head = 2 + (j >> 6);
    const int patch = j & 63;
    const int hb = patch >> 3, wb = patch & 7;
    const int base = (hb * 8) * 64 + wb * 8;
    const int nq = patch * 64 + wave * 16 + q16;
    const int t = nq & 63;
    const int n = base + ((t >> 3) << 6) + (t & 7);

    const bf16x8 qfrag = *reinterpret_cast<const bf16x8*>(
        xqkv + ((size_t)b * 4096 + n) * 768 + head * 32 + 8 * h);

    f32x4 o0 = {0.f,0.f,0.f,0.f}, o1 = {0.f,0.f,0.f,0.f}, o2 = {0.f,0.f,0.f,0.f};
    {
      const int nk = base + ((skey >> 3) << 6) + (skey & 7);
      const unsigned short* row = xqkv + ((size_t)b * 4096 + nk) * 768 + head * 32;
      *reinterpret_cast<bf16x8*>(&K_lds[skey][8 * sh]) =
          *reinterpret_cast<const bf16x8*>(row + 256 + 8 * sh);
      const bf16x8 v = *reinterpret_cast<const bf16x8*>(row + 512 + 8 * sh);
#pragma unroll
      for (int jj = 0; jj < 8; ++jj)
        V_lds[8 * sh + jj][skey] = (unsigned short)v[jj];
    }
    __syncthreads();

#pragma unroll
    for (int sub = 0; sub < 2; ++sub) {
      const int s32 = sub * 32;
      const bf16x8 k0 = *reinterpret_cast<const bf16x8*>(&K_lds[s32 + q16][8 * h]);
      const bf16x8 k1 = *reinterpret_cast<const bf16x8*>(&K_lds[s32 + 16 + q16][8 * h]);
      const bf16x4 va0 = *reinterpret_cast<const bf16x4*>(&V_lds[q16][s32 + 4 * h]);
      const bf16x4 vb0 = *reinterpret_cast<const bf16x4*>(&V_lds[q16][s32 + 16 + 4 * h]);
      const bf16x4 va1 = *reinterpret_cast<const bf16x4*>(&V_lds[16 + q16][s32 + 4 * h]);
      const bf16x4 vb1 = *reinterpret_cast<const bf16x4*>(&V_lds[16 + q16][s32 + 16 + 4 * h]);
      bf16x8 v0, v1;
#pragma unroll
      for (int i = 0; i < 4; ++i) {
        v0[i] = va0[i]; v0[4 + i] = vb0[i];
        v1[i] = va1[i]; v1[4 + i] = vb1[i];
      }
      tile_step_r22(k0, k1, v0, v1, ones, qfrag, o0, o1, o2);
    }

    const float inv = 1.f / o2[0];
    unsigned short* dst = attnb + ((size_t)b * 4096 + nq) * 256 + head * 32;
    uint2 w0, w1;
    w0.x = (unsigned)f2bf(o0[0] * inv) | ((unsigned)f2bf(o0[1] * inv) << 16);
    w0.y = (unsigned)f2bf(o0[2] * inv) | ((unsigned)f2bf(o0[3] * inv) << 16);
    w1.x = (unsigned)f2bf(o1[0] * inv) | ((unsigned)f2bf(o1[1] * inv) << 16);
    w1.y = (unsigned)f2bf(o1[2] * inv) | ((unsigned)f2bf(o1[3] * inv) << 16);
    *reinterpret_cast<uint2*>(dst + 4 * h) = w0;
    *reinterpret_cast<uint2*>(dst + 16 + 4 * h) = w1;
    return;
  }

  int head, lp, xb2, split, kstart, kend;
  if (fx < 128) {
    head = 6 + (fx >> 6);
    const int r = fx & 63;
    xb2 = r >> 2; split = r & 3; lp = 5;
    kstart = split * 256; kend = kstart + 256;
  } else {
    const int j = fx - 128;
    head = 4 + (j >> 4); xb2 = j & 15; split = 0; lp = 4;
    kstart = 0; kend = 256;
  }
  const int p = 1 << lp;
  const int pm1 = p - 1;
  const int P2 = p * p;
  const int nbp = 64 >> lp;
  const int patch = (xb2 * 256) >> (2 * lp);
  const int hb = patch / nbp, wb = patch - (patch / nbp) * nbp;
  const int base = ((hb << lp)) * 64 + (wb << lp);

  const int q0 = xb2 * 256 + wave * 64;
  const int nqA = q0 + q16, nqB = q0 + 16 + q16, nqC = q0 + 32 + q16, nqD = q0 + 48 + q16;

  bf16x8 qfA, qfB, qfC, qfD;
  {
    int tt = nqA & (P2 - 1);
    qfA = *reinterpret_cast<const bf16x8*>(
        xqkv + ((size_t)b * 4096 + base + ((tt >> lp) << 6) + (tt & pm1)) * 768 + head * 32 + 8 * h);
    tt = nqB & (P2 - 1);
    qfB = *reinterpret_cast<const bf16x8*>(
        xqkv + ((size_t)b * 4096 + base + ((tt >> lp) << 6) + (tt & pm1)) * 768 + head * 32 + 8 * h);
    tt = nqC & (P2 - 1);
    qfC = *reinterpret_cast<const bf16x8*>(
        xqkv + ((size_t)b * 4096 + base + ((tt >> lp) << 6) + (tt & pm1)) * 768 + head * 32 + 8 * h);
    tt = nqD & (P2 - 1);
    qfD = *reinterpret_cast<const bf16x8*>(
        xqkv + ((size_t)b * 4096 + base + ((tt >> lp) << 6) + (tt & pm1)) * 768 + head * 32 + 8 * h);
  }

  f32x4 o0A = {0.f,0.f,0.f,0.f}, o1A = {0.f,0.f,0.f,0.f}, o2A = {0.f,0.f,0.f,0.f};
  f32x4 o0B = {0.f,0.f,0.f,0.f}, o1B = {0.f,0.f,0.f,0.f}, o2B = {0.f,0.f,0.f,0.f};
  f32x4 o0C = {0.f,0.f,0.f,0.f}, o1C = {0.f,0.f,0.f,0.f}, o2C = {0.f,0.f,0.f,0.f};
  f32x4 o0D = {0.f,0.f,0.f,0.f}, o1D = {0.f,0.f,0.f,0.f}, o2D = {0.f,0.f,0.f,0.f};

  {
    const int kk = kstart + skey;
    const int nk0 = base + ((kk >> lp) << 6) + (kk & pm1);
    const unsigned short* row = xqkv + ((size_t)b * 4096 + nk0) * 768 + head * 32;
    const bf16x8 kr = *reinterpret_cast<const bf16x8*>(row + 256 + 8 * sh);
    const bf16x8 vr = *reinterpret_cast<const bf16x8*>(row + 512 + 8 * sh);
    *reinterpret_cast<bf16x8*>(&K_lds[skey][8 * sh]) = kr;
#pragma unroll
    for (int jj = 0; jj < 8; ++jj)
      V_lds[8 * sh + jj][skey] = (unsigned short)vr[jj];
  }
  __syncthreads();

  for (int kc = kstart; kc < kend; kc += 64) {
    const bool more = (kc + 64) < kend;
    bf16x8 krn = {}, vrn = {};
    if (more) {
      const int kk = kc + 64 + skey;
      const int nk = base + ((kk >> lp) << 6) + (kk & pm1);
      const unsigned short* row = xqkv + ((size_t)b * 4096 + nk) * 768 + head * 32;
      krn = *reinterpret_cast<const bf16x8*>(row + 256 + 8 * sh);
      vrn = *reinterpret_cast<const bf16x8*>(row + 512 + 8 * sh);
    }

#pragma unroll
    for (int sub = 0; sub < 2; ++sub) {
      const int s32 = sub * 32;
      const bf16x8 k0 = *reinterpret_cast<const bf16x8*>(&K_lds[s32 + q16][8 * h]);
      const bf16x8 k1 = *reinterpret_cast<const bf16x8*>(&K_lds[s32 + 16 + q16][8 * h]);
      const bf16x4 va0 = *reinterpret_cast<const bf16x4*>(&V_lds[q16][s32 + 4 * h]);
      const bf16x4 vb0 = *reinterpret_cast<const bf16x4*>(&V_lds[q16][s32 + 16 + 4 * h]);
      const bf16x4 va1 = *reinterpret_cast<const bf16x4*>(&V_lds[16 + q16][s32 + 4 * h]);
      const bf16x4 vb1 = *reinterpret_cast<const bf16x4*>(&V_lds[16 + q16][s32 + 16 + 4 * h]);
      bf16x8 v0, v1;
#pragma unroll
      for (int i = 0; i < 4; ++i) {
        v0[i] = va0[i]; v0[4 + i] = vb0[i];
        v1[i] = va1[i]; v1[4 + i] = vb1[i];
      }
      tile_step_r22(k0, k1, v0, v1, ones, qfA, o0A, o1A, o2A);
      tile_step_r22(k0, k1, v0, v1, ones, qfB, o0B, o1B, o2B);
      tile_step_r22(k0, k1, v0, v1, ones, qfC, o0C, o1C, o2C);
      tile_step_r22(k0, k1, v0, v1, ones, qfD, o0D, o1D, o2D);
    }
    __syncthreads();
    if (more) {
      *reinterpret_cast<bf16x8*>(&K_lds[skey][8 * sh]) = krn;
#pragma unroll
      for (int jj = 0; jj < 8; ++jj)
        V_lds[8 * sh + jj][skey] = (unsigned short)vrn[jj];
    }
    __syncthreads();
  }

  if (lp == 4) {
#define R22L_EPI(O0, O1, O2, NQ)                                               \
    {                                                                          \
      const float inv = 1.f / O2[0];                                           \
      unsigned short* dst = attnb + ((size_t)b * 4096 + (NQ)) * 256 + head * 32;\
      uint2 w0, w1;                                                            \
      w0.x = (unsigned)f2bf(O0[0] * inv) | ((unsigned)f2bf(O0[1] * inv) << 16);\
      w0.y = (unsigned)f2bf(O0[2] * inv) | ((unsigned)f2bf(O0[3] * inv) << 16);\
      w1.x = (unsigned)f2bf(O1[0] * inv) | ((unsigned)f2bf(O1[1] * inv) << 16);\
      w1.y = (unsigned)f2bf(O1[2] * inv) | ((unsigned)f2bf(O1[3] * inv) << 16);\
      *reinterpret_cast<uint2*>(dst + 4 * h) = w0;                             \
      *reinterpret_cast<uint2*>(dst + 16 + 4 * h) = w1;                        \
    }
    R22L_EPI(o0A, o1A, o2A, nqA)
    R22L_EPI(o0B, o1B, o2B, nqB)
    R22L_EPI(o0C, o1C, o2C, nqC)
    R22L_EPI(o0D, o1D, o2D, nqD)
#undef R22L_EPI
  } else {
    const int head2 = head - 6;
    const size_t pb0 = ((((size_t)split * 2 + head2) * 8 + b) * 4096);
#define R22P_EPI(O0, O1, O2, NQ)                                               \
    {                                                                          \
      float* dst = po + (pb0 + (NQ)) * 32;                                     \
      float4 w0, w1;                                                           \
      w0.x = O0[0]; w0.y = O0[1]; w0.z = O0[2]; w0.w = O0[3];                  \
      w1.x = O1[0]; w1.y = O1[1]; w1.z = O1[2]; w1.w = O1[3];                  \
      *reinterpret_cast<float4*>(dst + 4 * h) = w0;                            \
      *reinterpret_cast<float4*>(dst + 16 + 4 * h) = w1;                       \
      if (h == 0) pl[pb0 + (NQ)] = O2[0];                                      \
    }
    R22P_EPI(o0A, o1A, o2A, nqA)
    R22P_EPI(o0B, o1B, o2B, nqB)
    R22P_EPI(o0C, o1C, o2C, nqC)
    R22P_EPI(o0D, o1D, o2D, nqD)
#undef R22P_EPI
  }
}

// ---- combine p32 partials (4 splits) -> attnb -----------------------------
__global__ __launch_bounds__(256) void msa_p32comb_r22(
    const float* __restrict__ po, const float* __restrict__ pl,
    unsigned short* __restrict__ attnb)
{
  const int e = blockIdx.x * 256 + threadIdx.x;
  const int b = blockIdx.y;
  const int head2 = e >> 17;
  const int rem = e & 131071;
  const int nq = rem >> 5, c = rem & 31;
  const size_t i0 = ((((size_t)0 * 2 + head2) * 8 + b) * 4096 + nq);
  const size_t i1 = ((((size_t)1 * 2 + head2) * 8 + b) * 4096 + nq);
  const size_t i2 = ((((size_t)2 * 2 + head2) * 8 + b) * 4096 + nq);
  const size_t i3 = ((((size_t)3 * 2 + head2) * 8 + b) * 4096 + nq);
  const float o = (po[i0 * 32 + c] + po[i1 * 32 + c])
                + (po[i2 * 32 + c] + po[i3 * 32 + c]);
  const float l = (pl[i0] + pl[i1]) + (pl[i2] + pl[i3]);
  attnb[((size_t)b * 4096 + nq) * 256 + (6 + head2) * 32 + c] = f2bf(o / l);
}

// ---- GLOBAL attention with S=4 key split ----------------------------------
__global__ __launch_bounds__(256) void msa_attn_glob_r22(
    const unsigned short* __restrict__ Qg, const unsigned short* __restrict__ kv2,
    float* __restrict__ go, float* __restrict__ gll)
{
  __shared__ __align__(16) unsigned short K_lds[64][40];
  __shared__ __align__(16) unsigned short V_lds[32][68];

  const int tid = threadIdx.x;
  const int wave = tid >> 6, lane = tid & 63;
  const int q16 = lane & 15, h = lane >> 4;
  const int b = blockIdx.y;
  const int head = blockIdx.z;
  const int xb2 = blockIdx.x >> 2;
  const int split = blockIdx.x & 3;
  const int kstart = split * 256, kend = kstart + 256;

  bf16x8 ones;
#pragma unroll
  for (int i = 0; i < 8; ++i) ones[i] = (short)0x3F80;

  const int q0 = xb2 * 256 + wave * 64;
  const int nqA = q0 + q16, nqB = q0 + 16 + q16, nqC = q0 + 32 + q16, nqD = q0 + 48 + q16;

  const bf16x8 qfA = *reinterpret_cast<const bf16x8*>(
      Qg + ((size_t)b * 1024 + nqA) * 256 + head * 32 + 8 * h);
  const bf16x8 qfB = *reinterpret_cast<const bf16x8*>(
      Qg + ((size_t)b * 1024 + nqB) * 256 + head * 32 + 8 * h);
  const bf16x8 qfC = *reinterpret_cast<const bf16x8*>(
      Qg + ((size_t)b * 1024 + nqC) * 256 + head * 32 + 8 * h);
  const bf16x8 qfD = *reinterpret_cast<const bf16x8*>(
      Qg + ((size_t)b * 1024 + nqD) * 256 + head * 32 + 8 * h);

  f32x4 o0A = {0.f,0.f,0.f,0.f}, o1A = {0.f,0.f,0.f,0.f}, o2A = {0.f,0.f,0.f,0.f};
  f32x4 o0B = {0.f,0.f,0.f,0.f}, o1B = {0.f,0.f,0.f,0.f}, o2B = {0.f,0.f,0.f,0.f};
  f32x4 o0C = {0.f,0.f,0.f,0.f}, o1C = {0.f,0.f,0.f,0.f}, o2C = {0.f,0.f,0.f,0.f};
  f32x4 o0D = {0.f,0.f,0.f,0.f}, o1D = {0.f,0.f,0.f,0.f}, o2D = {0.f,0.f,0.f,0.f};

  const int skey = tid >> 2;
  const int sh = tid & 3;

  {
    const unsigned short* row = kv2 + ((size_t)b * 1024 + kstart + skey) * 512 + head * 32;
    const bf16x8 kr = *reinterpret_cast<const bf16x8*>(row + 8 * sh);
    const bf16x8 vr = *reinterpret_cast<const bf16x8*>(row + 256 + 8 * sh);
    *reinterpret_cast<bf16x8*>(&K_lds[skey][8 * sh]) = kr;
#pragma unroll
    for (int jj = 0; jj < 8; ++jj)
      V_lds[8 * sh + jj][skey] = (unsigned short)vr[jj];
  }
  __syncthreads();

  for (int kc = kstart; kc < kend; kc += 64) {
    const bool more = (kc + 64) < kend;
    bf16x8 krn = {}, vrn = {};
    if (more) {
      const unsigned short* row = kv2 + ((size_t)b * 1024 + kc + 64 + skey) * 512 + head * 32;
      krn = *reinterpret_cast<const bf16x8*>(row + 8 * sh);
      vrn = *reinterpret_cast<const bf16x8*>(row + 256 + 8 * sh);
    }

#pragma unroll
    for (int sub = 0; sub < 2; ++sub) {
      const int s32 = sub * 32;
      const bf16x8 k0 = *reinterpret_cast<const bf16x8*>(&K_lds[s32 + q16][8 * h]);
      const bf16x8 k1 = *reinterpret_cast<const bf16x8*>(&K_lds[s32 + 16 + q16][8 * h]);
      const bf16x4 va0 = *reinterpret_cast<const bf16x4*>(&V_lds[q16][s32 + 4 * h]);
      const bf16x4 vb0 = *reinterpret_cast<const bf16x4*>(&V_lds[q16][s32 + 16 + 4 * h]);
      const bf16x4 va1 = *reinterpret_cast<const bf16x4*>(&V_lds[16 + q16][s32 + 4 * h]);
      const bf16x4 vb1 = *reinterpret_cast<const bf16x4*>(&V_lds[16 + q16][s32 + 16 + 4 * h]);
      bf16x8 v0, v1;
#pragma unroll
      for (int i = 0; i < 4; ++i) {
        v0[i] = va0[i]; v0[4 + i] = vb0[i];
        v1[i] = va1[i]; v1[4 + i] = vb1[i];
      }
      tile_step_r22(k0, k1, v0, v1, ones, qfA, o0A, o1A, o2A);
      tile_step_r22(k0, k1, v0, v1, ones, qfB, o0B, o1B, o2B);
      tile_step_r22(k0, k1, v0, v1, ones, qfC, o0C, o1C, o2C);
      tile_step_r22(k0, k1, v0, v1, ones, qfD, o0D, o1D, o2D);
    }
    __syncthreads();
    if (more) {
      *reinterpret_cast<bf16x8*>(&K_lds[skey][8 * sh]) = krn;
#pragma unroll
      for (int jj = 0; jj < 8; ++jj)
        V_lds[8 * sh + jj][skey] = (unsigned short)vrn[jj];
    }
    __syncthreads();
  }

  const size_t gb0 = ((((size_t)split * 8 + b) * 8 + head) * 1024);
#define R22G_EPI(O0, O1, O2, NQ)                                               \
  {                                                                            \
    float* dst = go + (gb0 + (NQ)) * 32;                                       \
    float4 w0, w1;                                                             \
    w0.x = O0[0]; w0.y = O0[1]; w0.z = O0[2]; w0.w = O0[3];                    \
    w1.x = O1[0]; w1.y = O1[1]; w1.z = O1[2]; w1.w = O1[3];                    \
    *reinterpret_cast<float4*>(dst + 4 * h) = w0;                              \
    *reinterpret_cast<float4*>(dst + 16 + 4 * h) = w1;                         \
    if (h == 0) gll[gb0 + (NQ)] = O2[0];                                       \
  }
  R22G_EPI(o0A, o1A, o2A, nqA)
  R22G_EPI(o0B, o1B, o2B, nqB)
  R22G_EPI(o0C, o1C, o2C, nqC)
  R22G_EPI(o0D, o1D, o2D, nqD)
#undef R22G_EPI
}

// ---- combine global partials (4 splits) -> gl (f32) -----------------------
__global__ __launch_bounds__(256) void msa_globcomb_r22(
    const float* __restrict__ go, const float* __restrict__ gll,
    float* __restrict__ gl)
{
  const int e = blockIdx.x * 256 + threadIdx.x;
  const int b = blockIdx.y;
  const int head = e >> 15;
  const int rem = e & 32767;
  const int nq = rem >> 5, c = rem & 31;
  const size_t i0 = ((((size_t)0 * 8 + b) * 8 + head) * 1024 + nq);
  const size_t i1 = ((((size_t)1 * 8 + b) * 8 + head) * 1024 + nq);
  const size_t i2 = ((((size_t)2 * 8 + b) * 8 + head) * 1024 + nq);
  const size_t i3 = ((((size_t)3 * 8 + b) * 8 + head) * 1024 + nq);
  const float o = (go[i0 * 32 + c] + go[i1 * 32 + c])
                + (go[i2 * 32 + c] + go[i3 * 32 + c]);
  const float l = (gll[i0] + gll[i1]) + (gll[i2] + gll[i3]);
  gl[((size_t)b * 1024 + nq) * 256 + head * 32 + c] = o / l;
}

// ---- qg_reduce ------------------------------------------------------------
__global__ __launch_bounds__(256) void msa_qg_reduce_r22(
    const unsigned short* __restrict__ xqkv, float* __restrict__ qg_all)
{
  __shared__ float red[256];
  const int head = blockIdx.z;
  const int lp = (head < 2) ? 2 : (head < 4) ? 3 : (head < 6) ? 4 : 5;
  const int p = 1 << lp;
  const int P2 = p * p;
  const int nbp = 64 >> lp;
  const int npat = nbp * nbp;
  const int R = (lp <= 3) ? 8 : 1;
  const int total = P2 * 32 * R;
  const int gid = blockIdx.x * 256 + threadIdx.x;
  if (gid >= total) return;
  const int b = blockIdx.y;

  const int c = gid & 31;
  const int tr = gid >> 5;
  const int r = tr & (R - 1);
  const int t = tr >> ((R == 8) ? 3 : 0);
  const int hp = t >> lp, wp = t & (p - 1);

  const unsigned short* src = xqkv + (size_t)b * 4096 * 768 + head * 32 + c;
  float s = 0.f;
  for (int j = r; j < npat; j += R) {
    const int hb = j / nbp, wb = j - (j / nbp) * nbp;
    const int n = ((hb << lp) + hp) * 64 + (wb << lp) + wp;
    s += bf2f(src[(size_t)n * 768]);
  }

  if (R == 8) {
    red[threadIdx.x] = s;
    __syncthreads();
    if (r < 4) red[threadIdx.x] += red[threadIdx.x + 128];
    __syncthreads();
    if (r < 2) red[threadIdx.x] += red[threadIdx.x + 64];
    __syncthreads();
    if (r == 0) {
      s = red[threadIdx.x] + red[threadIdx.x + 32];
      qg_all[((size_t)b * 8 + head) * 32768 + (size_t)t * 32 + c] = s / (float)npat;
    }
  } else {
    qg_all[((size_t)b * 8 + head) * 32768 + (size_t)t * 32 + c] = s / (float)npat;
  }
}

// ---- bilinear upsample -> Qg bf16 -----------------------------------------
__global__ __launch_bounds__(256) void msa_qg_upsample_r22(
    const float* __restrict__ qg_all, unsigned short* __restrict__ Qg)
{
  const int head = blockIdx.z;
  const int p = (head < 2) ? 4 : (head < 4) ? 8 : (head < 6) ? 16 : 32;
  const int e = blockIdx.x * 256 + threadIdx.x;
  const int b = blockIdx.y;
  const int mlin = e >> 5, c = e & 31;
  const int mi = mlin >> 5, mj = mlin & 31;
  const float* src = qg_all + ((size_t)b * 8 + head) * 32768;
  float v;
  if (p == 32) {
    v = src[(size_t)mlin * 32 + c];
  } else {
    const float s = (float)p / 32.0f;
    const float xf = (mj + 0.5f) * s - 0.5f;
    const float yf = (mi + 0.5f) * s - 0.5f;
    const float xfl = floorf(xf), yfl = floorf(yf);
    const float fx = xf - xfl, fy = yf - yfl;
    const int x0 = (int)xfl, y0 = (int)yfl;
    const int x0c = max(0, min(p - 1, x0)), x1c = max(0, min(p - 1, x0 + 1));
    const int y0c = max(0, min(p - 1, y0)), y1c = max(0, min(p - 1, y0 + 1));
    const float v00 = src[(size_t)(y0c * p + x0c) * 32 + c];
    const float v01 = src[(size_t)(y0c * p + x1c) * 32 + c];
    const float v10 = src[(size_t)(y1c * p + x0c) * 32 + c];
    const float v11 = src[(size_t)(y1c * p + x1c) * 32 + c];
    v = (1.f - fy) * ((1.f - fx) * v00 + fx * v01)
      + fy * ((1.f - fx) * v10 + fx * v11);
  }
  Qg[((size_t)b * 1024 + mlin) * 256 + head * 32 + c] = f2bf(v);
}

// ---- 2x2 avg pool ---------------------------------------------------------
__global__ __launch_bounds__(256) void msa_pool_r22(
    const unsigned short* __restrict__ attn, unsigned short* __restrict__ pooled)
{
  const int c = threadIdx.x;
  const int mlin = blockIdx.x;
  const int b = blockIdx.y;
  const int mi = mlin >> 5, mj = mlin & 31;
  const size_t base = (size_t)b * 4096;
  const int r0 = mi * 2, q0 = mj * 2;
  float s = bf2f(attn[(base + (r0 * 64 + q0)) * 256 + c])
          + bf2f(attn[(base + (r0 * 64 + q0 + 1)) * 256 + c])
          + bf2f(attn[(base + ((r0 + 1) * 64 + q0)) * 256 + c])
          + bf2f(attn[(base + ((r0 + 1) * 64 + q0 + 1)) * 256 + c]);
  pooled[((size_t)b * 1024 + mlin) * 256 + c] = f2bf(s * 0.25f);
}

// ---- blend ----------------------------------------------------------------
__global__ __launch_bounds__(256) void msa_blend_r22(
    const float* __restrict__ gl, unsigned short* __restrict__ attn)
{
  const int c = threadIdx.x;
  const int n = blockIdx.x;
  const int b = blockIdx.y;
  const int hh = n >> 6, w = n & 63;
  const float xf = (w + 0.5f) * 0.5f - 0.5f;
  const float yf = (hh + 0.5f) * 0.5f - 0.5f;
  const float xfl = floorf(xf), yfl = floorf(yf);
  const float fx = xf - xfl, fy = yf - yfl;
  const int x0 = (int)xfl, y0 = (int)yfl;
  const int x0c = max(0, min(31, x0)), x1c = max(0, min(31, x0 + 1));
  const int y0c = max(0, min(31, y0)), y1c = max(0, min(31, y0 + 1));
  const float* g = gl + (size_t)b * 1024 * 256;
  const float v00 = g[(size_t)(y0c * 32 + x0c) * 256 + c];
  const float v01 = g[(size_t)(y0c * 32 + x1c) * 256 + c];
  const float v10 = g[(size_t)(y1c * 32 + x0c) * 256 + c];
  const float v11 = g[(size_t)(y1c * 32 + x1c) * 256 + c];
  const float v = (1.f - fy) * ((1.f - fx) * v00 + fx * v01)
                + fy * ((1.f - fx) * v10 + fx * v11);
  const size_t idx = ((size_t)b * 4096 + n) * 256 + c;
  attn[idx] = f2bf(bf2f(attn[idx]) + v);
}

extern "C" void kernel_launch(void* const* d_in, const int* in_sizes, int n_in,
                              void* d_out, int out_size, void* d_ws, size_t ws_size,
                              hipStream_t stream)
{
  const float* x     = (const float*)d_in[0];
  const float* Wq    = (const float*)d_in[1];
  const float* Wkv   = (const float*)d_in[2];
  const float* Wlkv  = (const float*)d_in[3];
  const float* Wproj = (const float*)d_in[4];
  const float* bproj = (const float*)d_in[5];

  char* ws = (char*)d_ws;
  unsigned short* xqkv  = (unsigned short*)(ws + 0);            // [32768,768] bf16
  unsigned short* attnb = (unsigned short*)(ws + 50331648ull);  // [32768,256] bf16
  unsigned short* Qg    = (unsigned short*)(ws + 67108864ull);  // [8192,256] bf16
  float* qg_all = (float*)(ws + 71303168ull);                   // [8,8,1024,32] f32
  unsigned short* Wqkvt = (unsigned short*)(ws + 79691776ull);  // [768,256] bf16
  unsigned short* Wlkvt = (unsigned short*)(ws + 80084992ull);  // [512,256] bf16
  unsigned short* Wprjt = (unsigned short*)(ws + 80347136ull);  // [256,256] bf16
  float* gl     = (float*)(ws + 80478208ull);                   // [8192,256] f32
  unsigned short* xb    = (unsigned short*)(ws + 88866816ull);  // [32768,256] bf16
  float* po  = (float*)(ws + 105644032ull);                     // [4][2][8][4096][32]
  float* pl  = (float*)(ws + 139198464ull);                     // [4][2][8][4096]
  float* go  = (float*)(ws + 105644032ull);                     // overlay po (dead after p32comb)
  float* gll = (float*)(ws + 139198464ull);                     // overlay pl
  unsigned short* pooled = (unsigned short*)(ws + 0);           // over dead xqkv
  unsigned short* kv2    = (unsigned short*)(ws + 16777216ull); // over dead xqkv

  // 0) merged casts
  msa_cast_r22<<<dim3(5632), 256, 0, stream>>>(x, Wq, Wkv, Wlkv, Wproj,
                                               xb, Wqkvt, Wlkvt, Wprjt);

  // 1) fused QKV projection (reg-dbuf GEMM; q cols CEXP-scaled)
  msa_gemm_mfma_r22<<<dim3(6, 256), 256, 0, stream>>>(
      xb, Wqkvt, nullptr, nullptr, xqkv, 256, 768, 256);

  // 2) global-query means + bilinear upsample
  msa_qg_reduce_r22<<<dim3(128, 8, 8), 256, 0, stream>>>(xqkv, qg_all);
  msa_qg_upsample_r22<<<dim3(128, 8, 8), 256, 0, stream>>>(qg_all, Qg);

  // 3) local windowed attention (p32 S=4, heavy-first) + combine
  msa_attn_local_r22<<<dim3(320, 8), 256, 0, stream>>>(xqkv, attnb, po, pl);
  msa_p32comb_r22<<<dim3(1024, 8), 256, 0, stream>>>(po, pl, attnb);

  // 4) pool + kv2 projection
  msa_pool_r22<<<dim3(1024, 8), 256, 0, stream>>>(attnb, pooled);
  msa_gemm_mfma_r22<<<dim3(4, 64), 256, 0, stream>>>(
      pooled, Wlkvt, nullptr, nullptr, kv2, 256, 512, 0);

  // 5) global cross-attention (S=4) + combine
  msa_attn_glob_r22<<<dim3(16, 8, 8), 256, 0, stream>>>(Qg, kv2, go, gll);
  msa_globcomb_r22<<<dim3(1024, 8), 256, 0, stream>>>(go, gll, gl);

  // 6) blend + final projection (reg-dbuf GEMM, fp32 out + bias)
  msa_blend_r22<<<dim3(4096, 8), 256, 0, stream>>>(gl, attnb);
  msa_gemm_mfma_r22<<<dim3(2, 256), 256, 0, stream>>>(
      attnb, Wprjt, bproj, (float*)d_out, nullptr, 256, 256, 0);

  (void)in_sizes; (void)n_in; (void)out_size; (void)ws_size;
}